// Round 4
// baseline (289.258 us; speedup 1.0000x reference)
//
#include <hip/hip_runtime.h>

typedef __attribute__((ext_vector_type(8)))  __bf16 bf16x8;
typedef __attribute__((ext_vector_type(4)))  __bf16 bf16x4;
typedef __attribute__((ext_vector_type(4)))  float  f32x4;
typedef __attribute__((ext_vector_type(16))) float  f32x16;
typedef __attribute__((ext_vector_type(4)))  int    i32x4;

static constexpr int TSEQ    = 2048;
static constexpr int DMODEL  = 1024;
static constexpr int HD      = 64;
static constexpr int VSTRIDE = 2080;   // V^T row stride (breaks 4KB L2-channel aliasing)

#define AS1 __attribute__((address_space(1)))
#define AS3 __attribute__((address_space(3)))
// XOR bank swizzle on 16B chunks within a 128B row (4 rows share each value per 32-row
// window -> every wave-wide b128/b64 access spreads evenly over all 32 banks).
#define SW(r) ((((r) & 12) >> 1) | ((r) & 1))

// ---------------- fused preprocessing: convert x + transpose weights ----------------
__global__ __launch_bounds__(256) void k_prep(const float* __restrict__ x,
    const float* __restrict__ w0, const float* __restrict__ w1,
    const float* __restrict__ w2, const float* __restrict__ w3,
    __bf16* __restrict__ xbf, __bf16* __restrict__ wt_all) {
  __shared__ float tile[32][33];
  const int blk = blockIdx.x;
  const int tid = threadIdx.x;
  if (blk < 4096) {
    size_t i = ((size_t)blk * 256 + tid) * 4;
    float4 v = *(const float4*)(x + i);
    bf16x4 o = { (__bf16)v.x, (__bf16)v.y, (__bf16)v.z, (__bf16)v.w };
    *(bf16x4*)(xbf + i) = o;
    return;
  }
  const int tz = blk - 4096;
  const int wi = tz >> 10;                 // which weight
  const int tl = tz & 1023;
  const int n0 = (tl & 31) * 32, k0 = (tl >> 5) * 32;
  const float* w = wi == 0 ? w0 : wi == 1 ? w1 : wi == 2 ? w2 : w3;
  __bf16* out = wt_all + (size_t)wi * DMODEL * DMODEL;
  const int tx = tid & 31, ty0 = (tid >> 5) * 4;
#pragma unroll
  for (int j = 0; j < 4; j++)
    tile[ty0 + j][tx] = w[(size_t)(k0 + ty0 + j) * DMODEL + n0 + tx];
  __syncthreads();
#pragma unroll
  for (int j = 0; j < 4; j++)
    out[(size_t)(n0 + ty0 + j) * DMODEL + k0 + tx] = (__bf16)tile[tx][ty0 + j];
}

// ---------------- m97-style GEMM mainloop (R6): global_load_lds width-16, BK=32 ----------------
__device__ __forceinline__ void gemm_mainloop(const __bf16* __restrict__ A,
                                              const __bf16* __restrict__ Bt,
                                              int bm, int bn,
                                              __bf16* At, __bf16* Bl,
                                              f32x4 acc[4][4]) {
  const int tid  = threadIdx.x;
  const int lane = tid & 63;
  const int l15  = lane & 15, quad = lane >> 4;
  const int wv   = tid >> 6;
  const int wm   = (wv >> 1) * 64, wn = (wv & 1) * 64;
  const int s0   = wv * 2;
  const int srow = lane >> 2;
  const int scol = (lane & 3) << 3;
  for (int k0 = 0; k0 < 1024; k0 += 32) {
    __syncthreads();
#pragma unroll
    for (int ss = 0; ss < 2; ss++) {
      const int s   = s0 + ss;
      const int row = s * 16 + srow;
      const __bf16* ga = A  + (size_t)(bm + row) * 1024 + k0 + scol;
      const __bf16* gb = Bt + (size_t)(bn + row) * 1024 + k0 + scol;
      __builtin_amdgcn_global_load_lds((const AS1 void*)ga,
                                       (AS3 void*)(At + s * 512), 16, 0, 0);
      __builtin_amdgcn_global_load_lds((const AS1 void*)gb,
                                       (AS3 void*)(Bl + s * 512), 16, 0, 0);
    }
    __syncthreads();
    bf16x8 af[4], bfr[4];
#pragma unroll
    for (int mt = 0; mt < 4; mt++)
      af[mt] = *(const bf16x8*)(At + (wm + mt * 16 + l15) * 32 + quad * 8);
#pragma unroll
    for (int nt = 0; nt < 4; nt++)
      bfr[nt] = *(const bf16x8*)(Bl + (wn + nt * 16 + l15) * 32 + quad * 8);
#pragma unroll
    for (int mt = 0; mt < 4; mt++)
#pragma unroll
      for (int nt = 0; nt < 4; nt++)
        acc[mt][nt] = __builtin_amdgcn_mfma_f32_16x16x32_bf16(
            af[mt], bfr[nt], acc[mt][nt], 0, 0, 0);
  }
}

// ---------------- QKV projection (Q pre-scaled by log2e/8; V stored transposed) ----------------
__global__ __launch_bounds__(256) void k_gemm_qkv(const __bf16* __restrict__ xbf,
    const __bf16* __restrict__ wt_all, __bf16* __restrict__ qws,
    __bf16* __restrict__ kws, __bf16* __restrict__ vtws) {
  __shared__ __bf16 At[128 * 32];
  __shared__ __bf16 Bl[128 * 32];
  const int which = blockIdx.z;
  const __bf16* wt = wt_all + (size_t)which * DMODEL * DMODEL;
  const int bm = blockIdx.y * 128, bn = blockIdx.x * 128;
  f32x4 acc[4][4];
  const f32x4 z = {0.f, 0.f, 0.f, 0.f};
#pragma unroll
  for (int mt = 0; mt < 4; mt++)
#pragma unroll
    for (int nt = 0; nt < 4; nt++) acc[mt][nt] = z;
  gemm_mainloop(xbf, wt, bm, bn, At, Bl, acc);
  const int lane = threadIdx.x & 63;
  const int l15 = lane & 15, quad = lane >> 4;
  const int wv = threadIdx.x >> 6;
  const int wm = (wv >> 1) * 64, wn = (wv & 1) * 64;
#pragma unroll
  for (int mt = 0; mt < 4; mt++)
#pragma unroll
    for (int nt = 0; nt < 4; nt++)
#pragma unroll
      for (int r = 0; r < 4; r++) {
        int m = bm + wm + mt * 16 + quad * 4 + r;
        int n = bn + wn + nt * 16 + l15;
        int b = m >> 11, t = m & 2047;
        int h = n >> 6,  d = n & 63;
        int bh = b * 16 + h;
        float av = acc[mt][nt][r];
        // 0.125 * log2(e): lets attention use v_exp_f32 (exp2) directly
        if (which == 0)      qws[((size_t)bh * TSEQ + t) * HD + d] = (__bf16)(av * 0.18033688f);
        else if (which == 1) kws[((size_t)bh * TSEQ + t) * HD + d] = (__bf16)av;
        else                 vtws[((size_t)bh * HD + d) * VSTRIDE + t] = (__bf16)av;
      }
}

// ---------------- flash attention (R10): wave-level K-split + sigma-permuted PV ----
// Block = 128-row q-band; 4 waves = (q-half qh, k-parity kpar). Wave (qh,kpar) computes
// tiles t = 2j+kpar for its 64 q-rows (2 m-reps of 32x32). No online max (exp2 of bounded
// scores) -> k-split is exact; partial (acc, l) merged once via 32KB LDS exchange.
// Staging: 4-deep LDS tile ring; parity-pair stages its own next tile via global_load_lds
// w16 with pre-swizzled SOURCE (linear dest, swizzled read). PV uses a permuted
// contraction order so the cvt_pk words feed the MFMA A-operand with ZERO cross-lane ops;
// V B-fragments read in sigma-order as 2x ds_read_b64 (bank-even).
// Pair (c, c+256) -> a + a' = 15: per-CU work uniform 17 steps, critical path 16.
__global__ __launch_bounds__(256) void k_attn(const __bf16* __restrict__ qws,
    const __bf16* __restrict__ kws, const __bf16* __restrict__ vtws,
    __bf16* __restrict__ ctx) {
  const int bh = blockIdx.x & 31;
  const int tr = blockIdx.x >> 5;
  const int a  = (tr < 8) ? (15 - tr) : (tr - 8);
  const int tid = threadIdx.x;
  const int lane = tid & 63;
  const int wv = tid >> 6;
  const int qh = wv & 1, kpar = wv >> 1;
  const int l31 = lane & 31, hi = lane >> 5;
  const __bf16* qp = qws  + (size_t)bh * TSEQ * HD;
  const __bf16* kp = kws  + (size_t)bh * TSEQ * HD;
  const __bf16* vp = vtws + (size_t)bh * HD * VSTRIDE;
  const int b = bh >> 4, h = bh & 15;
  const int qbase = a * 128 + qh * 64;        // this wave's 64 q-rows

  __shared__ __align__(16) __bf16 kbuf[4][64 * 64];
  __shared__ __align__(16) __bf16 vbuf[4][64 * 64];

  const int srl = lane >> 3;      // 0..7 (row within 8-row staging group)
  const int c8  = lane & 7;       // 16B chunk

  // stage rows [qh*32, qh*32+32) of tile t: linear LDS dest, inverse-swizzled gl source
  auto stage = [&](int t) {
    const int tb = t & 3;
#pragma unroll
    for (int g = 0; g < 4; g++) {
      const int row = qh * 32 + g * 8 + srl;
      const int swc = c8 ^ SW(row);
      __builtin_amdgcn_global_load_lds(
          (const AS1 void*)(kp + (size_t)(t * 64 + row) * HD + swc * 8),
          (AS3 void*)(&kbuf[tb][(qh * 32 + g * 8) * 64]), 16, 0, 0);
      __builtin_amdgcn_global_load_lds(
          (const AS1 void*)(vp + (size_t)row * VSTRIDE + t * 64 + swc * 8),
          (AS3 void*)(&vbuf[tb][(qh * 32 + g * 8) * 64]), 16, 0, 0);
    }
  };

  // Q fragments (B-operand of swapped QK): 2 m-reps x 4 d-slices
  bf16x8 aq[2][4];
#pragma unroll
  for (int m = 0; m < 2; m++)
#pragma unroll
    for (int ds = 0; ds < 4; ds++)
      aq[m][ds] = *(const bf16x8*)(qp + (size_t)(qbase + m * 32 + l31) * HD + ds * 16 + hi * 8);

  stage(kpar);                    // prologue: own parity's tile 0/1
  __syncthreads();

  const f32x16 z16 = {0.f,0.f,0.f,0.f,0.f,0.f,0.f,0.f,0.f,0.f,0.f,0.f,0.f,0.f,0.f,0.f};
  float lpart[2] = {0.f, 0.f};
  f32x16 acc[2][2];
  acc[0][0] = z16; acc[0][1] = z16; acc[1][0] = z16; acc[1][1] = z16;

  for (int j = 0; j <= a; j++) {
    const int t = 2 * j + kpar;
    if (j < a) stage(t + 2);                  // async, lands before end-of-step barrier
    if (t * 64 <= qbase + 63) {               // wave-relevance (wave-uniform)
      const __bf16* kb_ = kbuf[t & 3];
      const __bf16* vb_ = vbuf[t & 3];
#pragma unroll
      for (int kt = 0; kt < 2; kt++) {
        const int kts = t * 64 + kt * 32;
        const int krow = kt * 32 + l31;
        bf16x8 ak[4];
#pragma unroll
        for (int ds = 0; ds < 4; ds++)
          ak[ds] = *(const bf16x8*)(kb_ + krow * 64 + (((ds * 2 + hi) ^ SW(krow)) << 3));
        bf16x8 pa[2][2];
#pragma unroll
        for (int m = 0; m < 2; m++) {
          if (kts > qbase + m * 32 + 31) continue;     // sub-tile fully masked for m
          const int qg = qbase + m * 32 + l31;
          f32x16 s = z16;
#pragma unroll
          for (int ds = 0; ds < 4; ds++)
            s = __builtin_amdgcn_mfma_f32_32x32x16_bf16(ak[ds], aq[m][ds], s, 0, 0, 0);
          float pvv[16];
          if (kts + 31 <= qbase + m * 32) {            // fully unmasked (wave-uniform)
#pragma unroll
            for (int r = 0; r < 16; r++) {
              pvv[r] = __builtin_amdgcn_exp2f(s[r]);
              lpart[m] += pvv[r];
            }
          } else {
#pragma unroll
            for (int r = 0; r < 16; r++) {
              const int kg = kts + (r & 3) + 8 * (r >> 2) + 4 * hi;
              float p = (kg <= qg) ? __builtin_amdgcn_exp2f(s[r]) : 0.f;
              pvv[r] = p;
              lpart[m] += p;
            }
          }
          // pack to bf16 pairs; words feed the PV A-operand VERBATIM (sigma-order)
          int c[8];
#pragma unroll
          for (int jj = 0; jj < 8; jj++) {
            int w;
            asm("v_cvt_pk_bf16_f32 %0, %1, %2" : "=v"(w) : "v"(pvv[2 * jj]), "v"(pvv[2 * jj + 1]));
            c[jj] = w;
          }
          i32x4 w0 = { c[0], c[1], c[2], c[3] };
          i32x4 w1 = { c[4], c[5], c[6], c[7] };
          pa[m][0] = __builtin_bit_cast(bf16x8, w0);
          pa[m][1] = __builtin_bit_cast(bf16x8, w1);
        }
        // PV in sigma-order: B element j of slice s2 = V[kts + sigma(hi*8+j)][d].
        // sigma runs are 4-long -> two b64 reads per fragment (bank-even).
#pragma unroll
        for (int dt = 0; dt < 2; dt++) {
          const int vrow = dt * 32 + l31;
#pragma unroll
          for (int s2 = 0; s2 < 2; s2++) {
            bf16x4 blo = *(const bf16x4*)(vb_ + vrow * 64 +
                             (((kt * 4 + s2 * 2) ^ SW(vrow)) << 3) + 4 * hi);
            bf16x4 bhi = *(const bf16x4*)(vb_ + vrow * 64 +
                             (((kt * 4 + s2 * 2 + 1) ^ SW(vrow)) << 3) + 4 * hi);
            bf16x8 bv = __builtin_shufflevector(blo, bhi, 0, 1, 2, 3, 4, 5, 6, 7);
#pragma unroll
            for (int m = 0; m < 2; m++) {
              if (kts > qbase + m * 32 + 31) continue;
              acc[m][dt] = __builtin_amdgcn_mfma_f32_32x32x16_bf16(pa[m][s2], bv, acc[m][dt], 0, 0, 0);
            }
          }
        }
      }
    }
    __syncthreads();
  }

  // ---- merge k-parity partials: exchange (acc[.][give], l) through LDS ----
  float lf[2];
#pragma unroll
  for (int m = 0; m < 2; m++) lf[m] = lpart[m] + __shfl_xor(lpart[m], 32, 64);

  float* exch = (float*)&kbuf[0][0];     // 4 regions x 2m x 16r x 64 lanes = 32KB
  float* lsm  = (float*)&vbuf[0][0];     // 4 regions x 2m x 64 lanes = 2KB
  const int give = kpar ^ 1;
#pragma unroll
  for (int m = 0; m < 2; m++) {
#pragma unroll
    for (int r = 0; r < 16; r++)
      exch[((wv * 2 + m) * 16 + r) * 64 + lane] = acc[m][give][r];
    lsm[(wv * 2 + m) * 64 + lane] = lf[m];
  }
  __syncthreads();
  const int pwv = wv ^ 2;                // partner: same qh, other k-parity
#pragma unroll
  for (int m = 0; m < 2; m++) {
    const float lfin = lf[m] + lsm[(pwv * 2 + m) * 64 + lane];
#pragma unroll
    for (int r = 0; r < 16; r++) {
      const int ql = (r & 3) + 8 * (r >> 2) + 4 * hi;
      const float den  = __shfl(lfin, ql, 64);
      const float linv = __builtin_amdgcn_rcpf(den);
      const float val  = (acc[m][kpar][r] + exch[((pwv * 2 + m) * 16 + r) * 64 + lane]) * linv;
      const int qrow = qbase + m * 32 + ql;
      ctx[((size_t)(b * TSEQ + qrow)) * DMODEL + h * 64 + kpar * 32 + l31] = (__bf16)val;
    }
  }
}

// ---------------- output projection + bias (fp32 out) ----------------
__global__ __launch_bounds__(256) void k_gemm_out(const __bf16* __restrict__ ctx,
    const __bf16* __restrict__ wot, const float* __restrict__ bo,
    float* __restrict__ out) {
  __shared__ __bf16 At[128 * 32];
  __shared__ __bf16 Bl[128 * 32];
  const int bm = blockIdx.y * 128, bn = blockIdx.x * 128;
  f32x4 acc[4][4];
  const f32x4 z = {0.f, 0.f, 0.f, 0.f};
#pragma unroll
  for (int mt = 0; mt < 4; mt++)
#pragma unroll
    for (int nt = 0; nt < 4; nt++) acc[mt][nt] = z;
  gemm_mainloop(ctx, wot, bm, bn, At, Bl, acc);
  const int lane = threadIdx.x & 63;
  const int l15 = lane & 15, quad = lane >> 4;
  const int wv = threadIdx.x >> 6;
  const int wm = (wv >> 1) * 64, wn = (wv & 1) * 64;
#pragma unroll
  for (int mt = 0; mt < 4; mt++)
#pragma unroll
    for (int nt = 0; nt < 4; nt++)
#pragma unroll
      for (int r = 0; r < 4; r++) {
        int m = bm + wm + mt * 16 + quad * 4 + r;
        int n = bn + wn + nt * 16 + l15;
        out[(size_t)m * DMODEL + n] = acc[mt][nt][r] + bo[n];
      }
}

extern "C" void kernel_launch(void* const* d_in, const int* in_sizes, int n_in,
                              void* d_out, int out_size, void* d_ws, size_t ws_size,
                              hipStream_t stream) {
  const float* x  = (const float*)d_in[0];
  const float* Wq = (const float*)d_in[1];
  const float* Wk = (const float*)d_in[2];
  const float* Wv = (const float*)d_in[3];
  const float* Wo = (const float*)d_in[4];
  const float* bo = (const float*)d_in[5];
  float* out = (float*)d_out;

  __bf16* xbf  = (__bf16*)d_ws;                       // 4096*1024
  __bf16* wt   = xbf  + (size_t)4096 * 1024;          // 4 * 1024*1024
  __bf16* qws  = wt   + (size_t)4 * 1024 * 1024;      // [32][2048][64]
  __bf16* kws  = qws  + (size_t)32 * 2048 * 64;
  __bf16* vtws = kws  + (size_t)32 * 2048 * 64;       // [32][64][VSTRIDE]
  __bf16* ctx  = xbf;                                 // aliases xbf (dead after QKV)

  k_prep<<<8192, 256, 0, stream>>>(x, Wq, Wk, Wv, Wo, xbf, wt);
  k_gemm_qkv<<<dim3(8, 32, 3), 256, 0, stream>>>(xbf, wt, qws, kws, vtws);
  k_attn<<<512, 256, 0, stream>>>(qws, kws, vtws, ctx);
  k_gemm_out<<<dim3(8, 32), 256, 0, stream>>>(ctx, wt + (size_t)3 * 1024 * 1024, bo, out);
}

// Round 5
// 184.297 us; speedup vs baseline: 1.5695x; 1.5695x over previous
//
#include <hip/hip_runtime.h>

typedef __attribute__((ext_vector_type(8))) __bf16 bf16x8;
typedef __attribute__((ext_vector_type(4))) __bf16 bf16x4;
typedef __attribute__((ext_vector_type(4))) float  f32x4;

static constexpr int TSEQ    = 2048;
static constexpr int DMODEL  = 1024;
static constexpr int HD      = 64;
static constexpr int VSTRIDE = 2080;   // V^T row stride (breaks 4KB L2-channel aliasing)
static constexpr int LSTR    = 72;     // attn LDS row stride (36 dwords)

#define AS1 __attribute__((address_space(1)))
#define AS3 __attribute__((address_space(3)))

// ---------------- fused preprocessing: convert x + transpose weights ----------------
__global__ __launch_bounds__(256) void k_prep(const float* __restrict__ x,
    const float* __restrict__ w0, const float* __restrict__ w1,
    const float* __restrict__ w2, const float* __restrict__ w3,
    __bf16* __restrict__ xbf, __bf16* __restrict__ wt_all) {
  __shared__ float tile[32][33];
  const int blk = blockIdx.x;
  const int tid = threadIdx.x;
  if (blk < 4096) {
    size_t i = ((size_t)blk * 256 + tid) * 4;
    float4 v = *(const float4*)(x + i);
    bf16x4 o = { (__bf16)v.x, (__bf16)v.y, (__bf16)v.z, (__bf16)v.w };
    *(bf16x4*)(xbf + i) = o;
    return;
  }
  const int tz = blk - 4096;
  const int wi = tz >> 10;                 // which weight
  const int tl = tz & 1023;
  const int n0 = (tl & 31) * 32, k0 = (tl >> 5) * 32;
  const float* w = wi == 0 ? w0 : wi == 1 ? w1 : wi == 2 ? w2 : w3;
  __bf16* out = wt_all + (size_t)wi * DMODEL * DMODEL;
  const int tx = tid & 31, ty0 = (tid >> 5) * 4;
#pragma unroll
  for (int j = 0; j < 4; j++)
    tile[ty0 + j][tx] = w[(size_t)(k0 + ty0 + j) * DMODEL + n0 + tx];
  __syncthreads();
#pragma unroll
  for (int j = 0; j < 4; j++)
    out[(size_t)(n0 + ty0 + j) * DMODEL + k0 + tx] = (__bf16)tile[tx][ty0 + j];
}

// ---------------- pipelined GEMM mainloop (R11): dbuf LDS, 1 barrier/K-step,
// stage(k+1) issued before MFMA(k) so the barrier's vmcnt(0) drain is covered ----------
// NB = B-tile rows (128 for QKV, 64 for out-proj). NT = per-wave n-tiles = NB/32.
// Race check: single top-of-iter __syncthreads (drains each wave's own vm+lgkm counts)
// orders (a) all reads of buf^1 complete before any wave stages into buf^1, and
// (b) tile-k loads landed before tile-k ds_reads. No wave can run an iter ahead.
template <int NB>
__device__ __forceinline__ void gemm_mainloop_p(const __bf16* __restrict__ A,
                                                const __bf16* __restrict__ Bt,
                                                int bm, int bn,
                                                __bf16* At, __bf16* Bl,
                                                f32x4 acc[4][NB / 32]) {
  constexpr int NT = NB / 32;
  const int tid  = threadIdx.x;
  const int lane = tid & 63;
  const int l15  = lane & 15, quad = lane >> 4;
  const int wv   = tid >> 6;
  const int wm   = (wv >> 1) * 64, wn = (wv & 1) * (NT * 16);
  const int srow = lane >> 2;
  const int scol = (lane & 3) << 3;

  auto stage = [&](int k0, int hb) {
#pragma unroll
    for (int ss = 0; ss < 2; ss++) {
      const int s   = wv * 2 + ss;
      const int row = s * 16 + srow;
      __builtin_amdgcn_global_load_lds(
          (const AS1 void*)(A + (size_t)(bm + row) * 1024 + k0 + scol),
          (AS3 void*)(At + hb * 4096 + s * 512), 16, 0, 0);
    }
#pragma unroll
    for (int ss = 0; ss < NB / 64; ss++) {
      const int s   = wv * (NB / 64) + ss;
      const int row = s * 16 + srow;
      __builtin_amdgcn_global_load_lds(
          (const AS1 void*)(Bt + (size_t)(bn + row) * 1024 + k0 + scol),
          (AS3 void*)(Bl + hb * (NB * 32) + s * 512), 16, 0, 0);
    }
  };

  stage(0, 0);                            // prologue
  for (int k0 = 0; k0 < 1024; k0 += 32) {
    const int cur = (k0 >> 5) & 1;
    __syncthreads();                      // tile k landed; prior reads of buf^1 done
    bf16x8 af[4], bfr[NT];
#pragma unroll
    for (int mt = 0; mt < 4; mt++)
      af[mt] = *(const bf16x8*)(At + cur * 4096 + (wm + mt * 16 + l15) * 32 + quad * 8);
#pragma unroll
    for (int nt = 0; nt < NT; nt++)
      bfr[nt] = *(const bf16x8*)(Bl + cur * (NB * 32) + (wn + nt * 16 + l15) * 32 + quad * 8);
    if (k0 + 32 < 1024) stage(k0 + 32, cur ^ 1);   // overlap with MFMA below
#pragma unroll
    for (int mt = 0; mt < 4; mt++)
#pragma unroll
      for (int nt = 0; nt < NT; nt++)
        acc[mt][nt] = __builtin_amdgcn_mfma_f32_16x16x32_bf16(
            af[mt], bfr[nt], acc[mt][nt], 0, 0, 0);
  }
}

// ---------------- QKV projection (Q pre-scaled by log2e/8; V stored transposed) ----------------
__global__ __launch_bounds__(256) void k_gemm_qkv(const __bf16* __restrict__ xbf,
    const __bf16* __restrict__ wt_all, __bf16* __restrict__ qws,
    __bf16* __restrict__ kws, __bf16* __restrict__ vtws) {
  __shared__ __bf16 At[2 * 128 * 32];
  __shared__ __bf16 Bl[2 * 128 * 32];
  const int which = blockIdx.z;
  const __bf16* wt = wt_all + (size_t)which * DMODEL * DMODEL;
  const int bm = blockIdx.y * 128, bn = blockIdx.x * 128;
  f32x4 acc[4][4];
  const f32x4 z = {0.f, 0.f, 0.f, 0.f};
#pragma unroll
  for (int mt = 0; mt < 4; mt++)
#pragma unroll
    for (int nt = 0; nt < 4; nt++) acc[mt][nt] = z;
  gemm_mainloop_p<128>(xbf, wt, bm, bn, At, Bl, acc);
  const int lane = threadIdx.x & 63;
  const int l15 = lane & 15, quad = lane >> 4;
  const int wv = threadIdx.x >> 6;
  const int wm = (wv >> 1) * 64, wn = (wv & 1) * 64;
#pragma unroll
  for (int mt = 0; mt < 4; mt++)
#pragma unroll
    for (int nt = 0; nt < 4; nt++)
#pragma unroll
      for (int r = 0; r < 4; r++) {
        int m = bm + wm + mt * 16 + quad * 4 + r;
        int n = bn + wn + nt * 16 + l15;
        int b = m >> 11, t = m & 2047;
        int h = n >> 6,  d = n & 63;
        int bh = b * 16 + h;
        float av = acc[mt][nt][r];
        // 0.125 * log2(e): attention uses v_exp_f32 (exp2) directly
        if (which == 0)      qws[((size_t)bh * TSEQ + t) * HD + d] = (__bf16)(av * 0.18033688f);
        else if (which == 1) kws[((size_t)bh * TSEQ + t) * HD + d] = (__bf16)av;
        else                 vtws[((size_t)bh * HD + d) * VSTRIDE + t] = (__bf16)av;
      }
}

// ---------------- flash attention (R0 structure, verified 50.5us; exp2 instead of expf) ----
// 1D grid 512: bh = id & 31, qb0 = id >> 5. Round-robin dispatch puts all 16 blocks
// of a bh on XCD bh%8 -> 4 bh/XCD = 2MB K+V, L2-resident re-reads.
__global__ __launch_bounds__(256) void k_attn(const __bf16* __restrict__ qws,
    const __bf16* __restrict__ kws, const __bf16* __restrict__ vtws,
    __bf16* __restrict__ ctx) {
  const int bh  = blockIdx.x & 31;
  const int qb0 = blockIdx.x >> 5, qb1 = 31 - qb0;
  const int tid = threadIdx.x;
  const int lane = tid & 63, wv = tid >> 6;
  const int l15 = lane & 15, quad = lane >> 4;
  const __bf16* qp = qws  + (size_t)bh * TSEQ * HD;
  const __bf16* kp = kws  + (size_t)bh * TSEQ * HD;
  const __bf16* vp = vtws + (size_t)bh * HD * VSTRIDE;
  const int b = bh >> 4, h = bh & 15;

  __shared__ __bf16 kbuf[2][64 * LSTR];
  __shared__ __bf16 vbuf[2][64 * LSTR];
  __shared__ __bf16 plds[4][16 * LSTR];

  const f32x4 z = {0.f, 0.f, 0.f, 0.f};
  const int sr = tid >> 3, sc = (tid & 7) * 8;

  const int qr0a = qb0 * 64 + wv * 16;
  const int qr0b = qb1 * 64 + wv * 16;
  bf16x8 aq0[2], aq1[2];
#pragma unroll
  for (int kb = 0; kb < 2; kb++) {
    aq0[kb] = *(const bf16x8*)(qp + (size_t)(qr0a + l15) * HD + kb * 32 + quad * 8);
    aq1[kb] = *(const bf16x8*)(qp + (size_t)(qr0b + l15) * HD + kb * 32 + quad * 8);
  }

  bf16x8 kreg[2], vreg[2];
  kreg[0] = *(const bf16x8*)(kp + (size_t)sr * HD + sc);
  kreg[1] = *(const bf16x8*)(kp + (size_t)(sr + 32) * HD + sc);
  vreg[0] = *(const bf16x8*)(vp + (size_t)sr * VSTRIDE + sc);
  vreg[1] = *(const bf16x8*)(vp + (size_t)(sr + 32) * VSTRIDE + sc);
  *(bf16x8*)(kbuf[0] + sr * LSTR + sc)        = kreg[0];
  *(bf16x8*)(kbuf[0] + (sr + 32) * LSTR + sc) = kreg[1];
  *(bf16x8*)(vbuf[0] + sr * LSTR + sc)        = vreg[0];
  *(bf16x8*)(vbuf[0] + (sr + 32) * LSTR + sc) = vreg[1];
  __syncthreads();

  float lpart[4] = {0.f, 0.f, 0.f, 0.f};
  f32x4 acc[4];
#pragma unroll
  for (int dt = 0; dt < 4; dt++) acc[dt] = z;

  for (int s = 0; s < 33; s++) {
    const int cur = s & 1;
    const bool h0 = (s <= qb0);
    const bool masked = (s == qb0) || (s == 32);

    if (s + 1 < 33) {
      const int ktn = (s + 1 <= qb0) ? (s + 1) * 64 : (s - qb0) * 64;
      kreg[0] = *(const bf16x8*)(kp + (size_t)(ktn + sr) * HD + sc);
      kreg[1] = *(const bf16x8*)(kp + (size_t)(ktn + sr + 32) * HD + sc);
      vreg[0] = *(const bf16x8*)(vp + (size_t)sr * VSTRIDE + ktn + sc);
      vreg[1] = *(const bf16x8*)(vp + (size_t)(sr + 32) * VSTRIDE + ktn + sc);
    }

    const __bf16* kb_ = kbuf[cur];
    const __bf16* vb_ = vbuf[cur];
    f32x4 sarr[4];
#pragma unroll
    for (int nt = 0; nt < 4; nt++) sarr[nt] = z;
#pragma unroll
    for (int nt = 0; nt < 4; nt++)
#pragma unroll
      for (int kb = 0; kb < 2; kb++) {
        bf16x8 bk = *(const bf16x8*)(kb_ + (nt * 16 + l15) * LSTR + kb * 32 + quad * 8);
        bf16x8 a  = h0 ? aq0[kb] : aq1[kb];
        sarr[nt] = __builtin_amdgcn_mfma_f32_16x16x32_bf16(a, bk, sarr[nt], 0, 0, 0);
      }
    if (masked) {
#pragma unroll
      for (int r = 0; r < 4; r++) {
        const int qloc = wv * 16 + quad * 4 + r;
#pragma unroll
        for (int nt = 0; nt < 4; nt++) {
          int kloc = nt * 16 + l15;
          float p = (kloc <= qloc) ? __builtin_amdgcn_exp2f(sarr[nt][r]) : 0.f;
          lpart[r] += p;
          plds[wv][(quad * 4 + r) * LSTR + nt * 16 + l15] = (__bf16)p;
        }
      }
    } else {
#pragma unroll
      for (int r = 0; r < 4; r++)
#pragma unroll
        for (int nt = 0; nt < 4; nt++) {
          float p = __builtin_amdgcn_exp2f(sarr[nt][r]);
          lpart[r] += p;
          plds[wv][(quad * 4 + r) * LSTR + nt * 16 + l15] = (__bf16)p;
        }
    }
#pragma unroll
    for (int kb = 0; kb < 2; kb++) {
      bf16x8 ap = *(const bf16x8*)(&plds[wv][l15 * LSTR + kb * 32 + quad * 8]);
#pragma unroll
      for (int dt = 0; dt < 4; dt++) {
        bf16x8 bvv = *(const bf16x8*)(vb_ + (dt * 16 + l15) * LSTR + kb * 32 + quad * 8);
        acc[dt] = __builtin_amdgcn_mfma_f32_16x16x32_bf16(ap, bvv, acc[dt], 0, 0, 0);
      }
    }

    if (s + 1 < 33) {
      const int nxt = cur ^ 1;
      *(bf16x8*)(kbuf[nxt] + sr * LSTR + sc)        = kreg[0];
      *(bf16x8*)(kbuf[nxt] + (sr + 32) * LSTR + sc) = kreg[1];
      *(bf16x8*)(vbuf[nxt] + sr * LSTR + sc)        = vreg[0];
      *(bf16x8*)(vbuf[nxt] + (sr + 32) * LSTR + sc) = vreg[1];
    }
    __syncthreads();

    if (masked) {
      const int qr0 = h0 ? qr0a : qr0b;
#pragma unroll
      for (int r = 0; r < 4; r++) {
        float l = lpart[r];
        l += __shfl_xor(l, 1, 64);
        l += __shfl_xor(l, 2, 64);
        l += __shfl_xor(l, 4, 64);
        l += __shfl_xor(l, 8, 64);
        float linv = 1.f / l;
        const int qrow = qr0 + quad * 4 + r;
#pragma unroll
        for (int dt = 0; dt < 4; dt++)
          ctx[((size_t)(b * TSEQ + qrow)) * DMODEL + h * 64 + dt * 16 + l15] =
              (__bf16)(acc[dt][r] * linv);
        lpart[r] = 0.f;
      }
#pragma unroll
      for (int dt = 0; dt < 4; dt++) acc[dt] = z;
    }
  }
}

// ---------------- output projection + bias (fp32 out); 128x64 tiles -> 512 blocks ----------------
__global__ __launch_bounds__(256) void k_gemm_out(const __bf16* __restrict__ ctx,
    const __bf16* __restrict__ wot, const float* __restrict__ bo,
    float* __restrict__ out) {
  __shared__ __bf16 At[2 * 128 * 32];
  __shared__ __bf16 Bl[2 * 64 * 32];
  const int bm = blockIdx.y * 128, bn = blockIdx.x * 64;
  f32x4 acc[4][2];
  const f32x4 z = {0.f, 0.f, 0.f, 0.f};
#pragma unroll
  for (int mt = 0; mt < 4; mt++)
#pragma unroll
    for (int nt = 0; nt < 2; nt++) acc[mt][nt] = z;
  gemm_mainloop_p<64>(ctx, wot, bm, bn, At, Bl, acc);
  const int lane = threadIdx.x & 63;
  const int l15 = lane & 15, quad = lane >> 4;
  const int wv = threadIdx.x >> 6;
  const int wm = (wv >> 1) * 64, wn = (wv & 1) * 32;
#pragma unroll
  for (int mt = 0; mt < 4; mt++)
#pragma unroll
    for (int nt = 0; nt < 2; nt++)
#pragma unroll
      for (int r = 0; r < 4; r++) {
        int m = bm + wm + mt * 16 + quad * 4 + r;
        int n = bn + wn + nt * 16 + l15;
        out[(size_t)m * DMODEL + n] = acc[mt][nt][r] + bo[n];
      }
}

extern "C" void kernel_launch(void* const* d_in, const int* in_sizes, int n_in,
                              void* d_out, int out_size, void* d_ws, size_t ws_size,
                              hipStream_t stream) {
  const float* x  = (const float*)d_in[0];
  const float* Wq = (const float*)d_in[1];
  const float* Wk = (const float*)d_in[2];
  const float* Wv = (const float*)d_in[3];
  const float* Wo = (const float*)d_in[4];
  const float* bo = (const float*)d_in[5];
  float* out = (float*)d_out;

  __bf16* xbf  = (__bf16*)d_ws;                       // 4096*1024
  __bf16* wt   = xbf  + (size_t)4096 * 1024;          // 4 * 1024*1024
  __bf16* qws  = wt   + (size_t)4 * 1024 * 1024;      // [32][2048][64]
  __bf16* kws  = qws  + (size_t)32 * 2048 * 64;
  __bf16* vtws = kws  + (size_t)32 * 2048 * 64;       // [32][64][VSTRIDE]
  __bf16* ctx  = xbf;                                 // aliases xbf (dead after QKV)

  k_prep<<<8192, 256, 0, stream>>>(x, Wq, Wk, Wv, Wo, xbf, wt);
  k_gemm_qkv<<<dim3(8, 32, 3), 256, 0, stream>>>(xbf, wt, qws, kws, vtws);
  k_attn<<<512, 256, 0, stream>>>(qws, kws, vtws, ctx);
  k_gemm_out<<<dim3(16, 32), 256, 0, stream>>>(ctx, wt + (size_t)3 * 1024 * 1024, bo, out);
}